// Round 1
// baseline (12726.682 us; speedup 1.0000x reference)
//
#include <hip/hip_runtime.h>
#include <hip/hip_bf16.h>

// Problem constants
#define Bn 256
#define Tn 336
#define KE 16
#define Hn 512
#define Pn 256

typedef __attribute__((ext_vector_type(8))) __bf16 bf16x8;
typedef __attribute__((ext_vector_type(4))) float f32x4;

#define MFMA(a, b, c) __builtin_amdgcn_mfma_f32_16x16x32_bf16((a), (b), (c), 0, 0, 0)

// ---------------- pack kernels (once per launch) ----------------

// Wh [512,256] (k,n) -> WhT hi/lo [256][512] (n,k)
__global__ void pack_wh(const float* __restrict__ Wh, __bf16* __restrict__ hi,
                        __bf16* __restrict__ lo) {
    int i = blockIdx.x * 256 + threadIdx.x;  // 512*256
    int k = i >> 8, n = i & 255;
    float v = Wh[i];
    __bf16 h = (__bf16)v;
    hi[n * 512 + k] = h;
    lo[n * 512 + k] = (__bf16)(v - (float)h);
}

// Wx [17,256] -> WxTP [256][32] (n,k) zero-padded
__global__ void pack_wx(const float* __restrict__ Wx, __bf16* __restrict__ out) {
    int i = blockIdx.x * 256 + threadIdx.x;  // 256*32
    int n = i >> 5, k = i & 31;
    out[i] = (__bf16)((k < 17) ? Wx[k * 256 + n] : 0.f);
}

// same-layout fp32 -> bf16 hi/lo split
__global__ void pack_split(const float* __restrict__ in, __bf16* __restrict__ hi,
                           __bf16* __restrict__ lo, int n) {
    int i = blockIdx.x * 256 + threadIdx.x;
    if (i >= n) return;
    float v = in[i];
    __bf16 h = (__bf16)v;
    hi[i] = h;
    lo[i] = (__bf16)(v - (float)h);
}

// Xin packed time-major: [T][B][32] bf16, k=0 -> x_l, k=1..16 -> x_ext, else 0
__global__ void pack_xin(const float* __restrict__ xl, const float* __restrict__ xe,
                         __bf16* __restrict__ out) {
    int i = blockIdx.x * 256 + threadIdx.x;  // 336*256*32
    int k = i & 31, b = (i >> 5) & 255, t = i >> 13;
    float v = 0.f;
    if (k == 0) v = xl[b * Tn + t];
    else if (k < 17) v = xe[(b * Tn + t) * KE + (k - 1)];
    out[i] = (__bf16)v;
}

// ---------------- per-step kernels ----------------

// x' = tanh(h @ Wh + xin @ Wx + b_t)  -> xp bf16 [256][256]
// grid (4,4), 256 thr; block tile 64x64; wave tile 32x32 (2x2 frags)
__global__ __launch_bounds__(256) void k1_xprime(
    const __bf16* __restrict__ hbf,                                  // [256][512]
    const __bf16* __restrict__ WhT_hi, const __bf16* __restrict__ WhT_lo,  // [256][512]
    const __bf16* __restrict__ WxTP,                                 // [256][32]
    const __bf16* __restrict__ XinP_t,                               // [256][32]
    const float* __restrict__ b_t,                                   // [256]
    __bf16* __restrict__ xp)                                         // [256][256]
{
    const int lane = threadIdx.x & 63;
    const int w = threadIdx.x >> 6;
    const int wm = w >> 1, wn = w & 1;
    const int m_base = blockIdx.y * 64 + wm * 32;
    const int n_base = blockIdx.x * 64 + wn * 32;
    const int lr = lane & 15;
    const int ko = (lane >> 4) << 3;

    f32x4 acc[2][2] = {};

    const __bf16* A0 = hbf + (size_t)(m_base + lr) * 512 + ko;
    const __bf16* Bh = WhT_hi + (size_t)(n_base + lr) * 512 + ko;
    const __bf16* Bl = WhT_lo + (size_t)(n_base + lr) * 512 + ko;

#pragma unroll
    for (int k0 = 0; k0 < 512; k0 += 32) {
        bf16x8 a0 = *(const bf16x8*)(A0 + k0);
        bf16x8 a1 = *(const bf16x8*)(A0 + 16 * 512 + k0);
        bf16x8 bh0 = *(const bf16x8*)(Bh + k0);
        bf16x8 bh1 = *(const bf16x8*)(Bh + 16 * 512 + k0);
        bf16x8 bl0 = *(const bf16x8*)(Bl + k0);
        bf16x8 bl1 = *(const bf16x8*)(Bl + 16 * 512 + k0);
        acc[0][0] = MFMA(a0, bh0, acc[0][0]);
        acc[0][0] = MFMA(a0, bl0, acc[0][0]);
        acc[0][1] = MFMA(a0, bh1, acc[0][1]);
        acc[0][1] = MFMA(a0, bl1, acc[0][1]);
        acc[1][0] = MFMA(a1, bh0, acc[1][0]);
        acc[1][0] = MFMA(a1, bl0, acc[1][0]);
        acc[1][1] = MFMA(a1, bh1, acc[1][1]);
        acc[1][1] = MFMA(a1, bl1, acc[1][1]);
    }
    // xin tail (K padded to 32, Wx single bf16 — error negligible)
    {
        bf16x8 a0 = *(const bf16x8*)(XinP_t + (size_t)(m_base + lr) * 32 + ko);
        bf16x8 a1 = *(const bf16x8*)(XinP_t + (size_t)(m_base + 16 + lr) * 32 + ko);
        bf16x8 b0 = *(const bf16x8*)(WxTP + (size_t)(n_base + lr) * 32 + ko);
        bf16x8 b1 = *(const bf16x8*)(WxTP + (size_t)(n_base + 16 + lr) * 32 + ko);
        acc[0][0] = MFMA(a0, b0, acc[0][0]);
        acc[0][1] = MFMA(a0, b1, acc[0][1]);
        acc[1][0] = MFMA(a1, b0, acc[1][0]);
        acc[1][1] = MFMA(a1, b1, acc[1][1]);
    }

    const int rbase = (lane >> 4) * 4;
#pragma unroll
    for (int i = 0; i < 2; ++i) {
#pragma unroll
        for (int j = 0; j < 2; ++j) {
            int col = n_base + j * 16 + lr;
            float bt = b_t[col];
#pragma unroll
            for (int r = 0; r < 4; ++r) {
                int row = m_base + i * 16 + rbase + r;
                float v = acc[i][j][r] + bt;
                float e = __expf(2.f * v);
                float tv = 1.f - 2.f / (e + 1.f);  // tanh
                xp[(size_t)row * 256 + col] = (__bf16)tv;
            }
        }
    }
}

// gates + GRU update. grid (16,4): blockIdx.x = unit tile (32 units),
// blockIdx.y = row tile (64 rows). wave = 32 rows x 16 units, 3 gates.
__global__ __launch_bounds__(256) void k2_gru(
    const __bf16* __restrict__ xp,   // [256][256]
    const __bf16* __restrict__ hbf,  // [256][512]
    const float* __restrict__ hf,    // [256][512]
    const __bf16* __restrict__ Wih_hi, const __bf16* __restrict__ Wih_lo,  // [1536][256]
    const __bf16* __restrict__ Whh_hi, const __bf16* __restrict__ Whh_lo,  // [1536][512]
    const float* __restrict__ b_ih, const float* __restrict__ b_hh,        // [1536]
    float* __restrict__ hf_n, __bf16* __restrict__ hbf_n)
{
    const int lane = threadIdx.x & 63;
    const int w = threadIdx.x >> 6;
    const int wm = w >> 1, wn = w & 1;
    const int m_base = blockIdx.y * 64 + wm * 32;
    const int u_base = blockIdx.x * 32 + wn * 16;
    const int lr = lane & 15;
    const int ko = (lane >> 4) << 3;

    f32x4 ax[3][2] = {};  // x'-segment accum (r,z,n)
    f32x4 ah[3][2] = {};  // h-segment accum (r,z,n)

    // segment 1: K=256 over x'
    {
        const __bf16* A = xp + (size_t)(m_base + lr) * 256 + ko;
        const __bf16* B0 = Wih_hi + (size_t)(u_base + lr) * 256 + ko;
        const __bf16* B1 = Wih_lo + (size_t)(u_base + lr) * 256 + ko;
#pragma unroll
        for (int k0 = 0; k0 < 256; k0 += 32) {
            bf16x8 a0 = *(const bf16x8*)(A + k0);
            bf16x8 a1 = *(const bf16x8*)(A + 16 * 256 + k0);
#pragma unroll
            for (int g = 0; g < 3; ++g) {
                bf16x8 bh = *(const bf16x8*)(B0 + (size_t)g * 512 * 256 + k0);
                bf16x8 bl = *(const bf16x8*)(B1 + (size_t)g * 512 * 256 + k0);
                ax[g][0] = MFMA(a0, bh, ax[g][0]);
                ax[g][0] = MFMA(a0, bl, ax[g][0]);
                ax[g][1] = MFMA(a1, bh, ax[g][1]);
                ax[g][1] = MFMA(a1, bl, ax[g][1]);
            }
        }
    }
    // segment 2: K=512 over h
    {
        const __bf16* A = hbf + (size_t)(m_base + lr) * 512 + ko;
        const __bf16* B0 = Whh_hi + (size_t)(u_base + lr) * 512 + ko;
        const __bf16* B1 = Whh_lo + (size_t)(u_base + lr) * 512 + ko;
#pragma unroll
        for (int k0 = 0; k0 < 512; k0 += 32) {
            bf16x8 a0 = *(const bf16x8*)(A + k0);
            bf16x8 a1 = *(const bf16x8*)(A + 16 * 512 + k0);
#pragma unroll
            for (int g = 0; g < 3; ++g) {
                bf16x8 bh = *(const bf16x8*)(B0 + (size_t)g * 512 * 512 + k0);
                bf16x8 bl = *(const bf16x8*)(B1 + (size_t)g * 512 * 512 + k0);
                ah[g][0] = MFMA(a0, bh, ah[g][0]);
                ah[g][0] = MFMA(a0, bl, ah[g][0]);
                ah[g][1] = MFMA(a1, bh, ah[g][1]);
                ah[g][1] = MFMA(a1, bl, ah[g][1]);
            }
        }
    }

    // epilogue: GRU elementwise
    const int rbase = (lane >> 4) * 4;
    const int u = u_base + lr;
    const float bihr = b_ih[u], bhhr = b_hh[u];
    const float bihz = b_ih[512 + u], bhhz = b_hh[512 + u];
    const float bihn = b_ih[1024 + u], bhhn = b_hh[1024 + u];
#pragma unroll
    for (int i = 0; i < 2; ++i) {
#pragma unroll
        for (int r = 0; r < 4; ++r) {
            int b = m_base + i * 16 + rbase + r;
            float pr = ax[0][i][r] + ah[0][i][r] + bihr + bhhr;
            float pz = ax[1][i][r] + ah[1][i][r] + bihz + bhhz;
            float xn = ax[2][i][r] + bihn;
            float hn = ah[2][i][r] + bhhn;
            float rr = 1.f / (1.f + __expf(-pr));
            float zz = 1.f / (1.f + __expf(-pz));
            float arg = xn + rr * hn;
            float e = __expf(2.f * arg);
            float nn = 1.f - 2.f / (e + 1.f);  // tanh
            float ho = hf[(size_t)b * 512 + u];
            float hnew = (1.f - zz) * nn + zz * ho;
            hf_n[(size_t)b * 512 + u] = hnew;
            hbf_n[(size_t)b * 512 + u] = (__bf16)hnew;
        }
    }
}

// ---------------- host launcher ----------------

extern "C" void kernel_launch(void* const* d_in, const int* in_sizes, int n_in,
                              void* d_out, int out_size, void* d_ws, size_t ws_size,
                              hipStream_t stream) {
    const float* x_l = (const float*)d_in[0];
    const float* x_e = (const float*)d_in[1];
    const float* Wh  = (const float*)d_in[2];
    const float* Wx  = (const float*)d_in[3];
    const float* bt  = (const float*)d_in[4];
    const float* Wih = (const float*)d_in[5];
    const float* Whh = (const float*)d_in[6];
    const float* bih = (const float*)d_in[7];
    const float* bhh = (const float*)d_in[8];

    char* ws = (char*)d_ws;
    __bf16* WhT_hi = (__bf16*)(ws + 0);          //  262144
    __bf16* WhT_lo = (__bf16*)(ws + 262144);     //  262144
    __bf16* WxTP   = (__bf16*)(ws + 524288);     //   16384
    __bf16* Wih_hi = (__bf16*)(ws + 540672);     //  786432
    __bf16* Wih_lo = (__bf16*)(ws + 1327104);    //  786432
    __bf16* Whh_hi = (__bf16*)(ws + 2113536);    // 1572864
    __bf16* Whh_lo = (__bf16*)(ws + 3686400);    // 1572864
    __bf16* XinP   = (__bf16*)(ws + 5259264);    // 5505024
    __bf16* xp     = (__bf16*)(ws + 10764288);   //  131072
    __bf16* hbf0   = (__bf16*)(ws + 10895360);   //  262144
    __bf16* hbf1   = (__bf16*)(ws + 11157504);   //  262144
    float*  hf0    = (float*) (ws + 11419648);   //  524288
    float*  hf1    = (float*) (ws + 11943936);   //  524288  -> total ~12.5 MB

    // one-time packing (graph-captured, cheap)
    pack_wh<<<512, 256, 0, stream>>>(Wh, WhT_hi, WhT_lo);
    pack_wx<<<32, 256, 0, stream>>>(Wx, WxTP);
    pack_split<<<1536, 256, 0, stream>>>(Wih, Wih_hi, Wih_lo, 1536 * 256);
    pack_split<<<3072, 256, 0, stream>>>(Whh, Whh_hi, Whh_lo, 1536 * 512);
    pack_xin<<<10752, 256, 0, stream>>>(x_l, x_e, XinP);
    hipMemsetAsync(hbf0, 0, 262144, stream);
    hipMemsetAsync(hf0, 0, 524288, stream);

    __bf16* hbf[2] = {hbf0, hbf1};
    float*  hff[2] = {hf0, hf1};

    for (int t = 0; t < Tn; ++t) {
        int c = t & 1, nx = c ^ 1;
        k1_xprime<<<dim3(4, 4), 256, 0, stream>>>(
            hbf[c], WhT_hi, WhT_lo, WxTP, XinP + (size_t)t * Bn * 32, bt, xp);
        float* hfn = (t == Tn - 1) ? (float*)d_out : hff[nx];
        k2_gru<<<dim3(16, 4), 256, 0, stream>>>(
            xp, hbf[c], hff[c], Wih_hi, Wih_lo, Whh_hi, Whh_lo, bih, bhh,
            hfn, hbf[nx]);
    }
}